// Round 1
// baseline (346.871 us; speedup 1.0000x reference)
//
#include <hip/hip_runtime.h>
#include <hip/hip_bf16.h>
#include <math.h>

typedef __attribute__((ext_vector_type(8))) short bf16x8;
typedef __attribute__((ext_vector_type(8))) unsigned short u16x8;
typedef __attribute__((ext_vector_type(4))) float f32x4;

__device__ __forceinline__ unsigned short f2bf(float f) {
  union { float f; unsigned u; } c; c.f = f;
  unsigned u = c.u;
  u += 0x7fffu + ((u >> 16) & 1u);   // round-to-nearest-even
  return (unsigned short)(u >> 16);
}

// ---------------- cast fp32 -> bf16 (vectorized) ----------------
__global__ __launch_bounds__(256) void cast_kernel(const float* __restrict__ in,
                                                   unsigned short* __restrict__ out,
                                                   int n4) {
  int i = blockIdx.x * 256 + threadIdx.x;
  if (i >= n4) return;
  float4 v = ((const float4*)in)[i];
  ushort4 o;
  o.x = f2bf(v.x); o.y = f2bf(v.y); o.z = f2bf(v.z); o.w = f2bf(v.w);
  ((ushort4*)out)[i] = o;
}

// ------------- transpose+cast 1024x1024 fp32 -> bf16 (N x K) -------------
// z=0..2: Wq,Wk,Wv -> Wqkvt rows [z*1024, z*1024+1024);  z=3: Wo -> Wot
__global__ __launch_bounds__(256) void transpose_cast(
    const float* __restrict__ Wq, const float* __restrict__ Wk,
    const float* __restrict__ Wv, const float* __restrict__ Wo,
    unsigned short* __restrict__ Wqkvt, unsigned short* __restrict__ Wot) {
  __shared__ float t[32][33];
  int z = blockIdx.z;
  const float* src = (z == 0) ? Wq : (z == 1) ? Wk : (z == 2) ? Wv : Wo;
  unsigned short* dst = (z < 3) ? (Wqkvt + (size_t)z * 1024 * 1024) : Wot;
  int tx = threadIdx.x & 31, ty = threadIdx.x >> 5;
  int bx = blockIdx.x, by = blockIdx.y;  // bx: n-tile, by: k-tile
#pragma unroll
  for (int i = 0; i < 4; ++i)
    t[ty + i * 8][tx] = src[(size_t)(by * 32 + ty + i * 8) * 1024 + bx * 32 + tx];
  __syncthreads();
#pragma unroll
  for (int i = 0; i < 4; ++i)
    dst[(size_t)(bx * 32 + ty + i * 8) * 1024 + by * 32 + tx] = f2bf(t[tx][ty + i * 8]);
}

// ---------------- bf16 GEMM: C[M][N] = A[M][K] * Bt[N][K]^T (+bias) ----------------
// 128x128 block tile, BK=32, 4 waves (2x2 of 64x64), 16x16x32 MFMA.
template <int BF16_OUT, int ADD_BIAS>
__global__ __launch_bounds__(256) void gemm_bt(
    const unsigned short* __restrict__ A, const unsigned short* __restrict__ Bt,
    void* __restrict__ Cout, const float* __restrict__ bias, int M, int N, int K) {
  __shared__ unsigned short As[128][40];  // 40-pad: b128 reads are 2-way max (free)
  __shared__ unsigned short Bs[128][40];
  const int tid = threadIdx.x;
  const int wave = tid >> 6, lane = tid & 63;
  const int quad = lane >> 4, l16 = lane & 15;
  const int m0 = blockIdx.y * 128, n0 = blockIdx.x * 128;
  const int wm = (wave >> 1) * 64, wn = (wave & 1) * 64;
  f32x4 acc[4][4] = {};

  for (int k0 = 0; k0 < K; k0 += 32) {
    __syncthreads();
#pragma unroll
    for (int cc = 0; cc < 2; ++cc) {  // 512 16B chunks per operand tile / 256 threads
      int c = tid + cc * 256;
      int row = c >> 2, ch = (c & 3) * 8;
      *(u16x8*)&As[row][ch] = *(const u16x8*)(A + (size_t)(m0 + row) * K + k0 + ch);
      *(u16x8*)&Bs[row][ch] = *(const u16x8*)(Bt + (size_t)(n0 + row) * K + k0 + ch);
    }
    __syncthreads();
    bf16x8 af[4], bfr[4];
#pragma unroll
    for (int i = 0; i < 4; ++i) {
      af[i]  = *(const bf16x8*)&As[wm + i * 16 + l16][quad * 8];
      bfr[i] = *(const bf16x8*)&Bs[wn + i * 16 + l16][quad * 8];
    }
#pragma unroll
    for (int mi = 0; mi < 4; ++mi)
#pragma unroll
      for (int ni = 0; ni < 4; ++ni)
        acc[mi][ni] = __builtin_amdgcn_mfma_f32_16x16x32_bf16(af[mi], bfr[ni], acc[mi][ni], 0, 0, 0);
  }

#pragma unroll
  for (int mi = 0; mi < 4; ++mi) {
#pragma unroll
    for (int ni = 0; ni < 4; ++ni) {
      int col = n0 + wn + ni * 16 + l16;
      float bv = ADD_BIAS ? bias[col] : 0.0f;
#pragma unroll
      for (int r = 0; r < 4; ++r) {
        int row = m0 + wm + mi * 16 + quad * 4 + r;  // C/D: row=quad*4+reg, col=lane&15
        float v = acc[mi][ni][r] + bv;
        if (BF16_OUT) ((unsigned short*)Cout)[(size_t)row * N + col] = f2bf(v);
        else          ((float*)Cout)[(size_t)row * N + col] = v;
      }
    }
  }
}

// ---------------- causal flash attention ----------------
// QKV: [4096][3072] bf16 rows = [q(1024)|k(1024)|v(1024)], token t = b*2048+s.
// grid: (S/64, B*H). 4 waves/block, 16 queries/wave, 32-key tiles.
__global__ __launch_bounds__(256) void attn_kernel(const unsigned short* __restrict__ QKV,
                                                   unsigned short* __restrict__ ctx) {
  const int ROWSTR = 3072;
  const int b = blockIdx.y >> 4, h = blockIdx.y & 15;
  const int wave = threadIdx.x >> 6, lane = threadIdx.x & 63;
  const int quad = lane >> 4, l16 = lane & 15;
  const int q0 = blockIdx.x * 64 + wave * 16;
  const unsigned short* base = QKV + (size_t)b * 2048 * ROWSTR;
  const unsigned short* Qp = base + h * 64;
  const unsigned short* Kp = base + 1024 + h * 64;
  const unsigned short* Vp = base + 2048 + h * 64;
  __shared__ unsigned short Vs[32][66];      // 66-pad: PV B-frag gather conflict-free
  __shared__ unsigned short Ps[4][16][40];   // per-wave P round-trip (C-layout -> A-layout)

  bf16x8 qf[2];  // A-frag: m=lane&15 (query), k=quad*8+j (dim), kk*32 halves
#pragma unroll
  for (int kk = 0; kk < 2; ++kk)
    qf[kk] = *(const bf16x8*)(Qp + (size_t)(q0 + l16) * ROWSTR + kk * 32 + quad * 8);

  f32x4 o[4] = {};
  float mrow[4], lrow[4];
#pragma unroll
  for (int r = 0; r < 4; ++r) { mrow[r] = -INFINITY; lrow[r] = 0.f; }

  const int ntiles = (blockIdx.x + 1) * 2;  // uniform across block: __syncthreads legal
  for (int kt = 0; kt < ntiles; ++kt) {
    const int k0 = kt * 32;
    // ---- S = Q K^T (two 16-key groups x two 32-dim halves) ----
    f32x4 sc[2] = {};
#pragma unroll
    for (int g = 0; g < 2; ++g)
#pragma unroll
      for (int kk = 0; kk < 2; ++kk) {
        bf16x8 kf = *(const bf16x8*)(Kp + (size_t)(k0 + g * 16 + l16) * ROWSTR + kk * 32 + quad * 8);
        sc[g] = __builtin_amdgcn_mfma_f32_16x16x32_bf16(qf[kk], kf, sc[g], 0, 0, 0);
      }
    // ---- stage V tile 32x64 ----
    __syncthreads();  // previous iteration's Vs readers done
    {
      int key = threadIdx.x >> 3;
      int d8 = (threadIdx.x & 7) * 8;
      u16x8 v = *(const u16x8*)(Vp + (size_t)(k0 + key) * ROWSTR + d8);
      unsigned* dst = (unsigned*)&Vs[key][d8];
      const unsigned* sv = (const unsigned*)&v;
      dst[0] = sv[0]; dst[1] = sv[1]; dst[2] = sv[2]; dst[3] = sv[3];
    }
    __syncthreads();  // Vs ready
    // ---- scale + causal mask (C/D: row=quad*4+r is query, col=l16 is key) ----
    const int qb = q0 + quad * 4;
#pragma unroll
    for (int g = 0; g < 2; ++g) {
      int key = k0 + g * 16 + l16;
#pragma unroll
      for (int r = 0; r < 4; ++r) {
        float s = sc[g][r] * 0.125f;
        sc[g][r] = (key <= qb + r) ? s : -INFINITY;
      }
    }
    // ---- online softmax ----
    float mx[4];
#pragma unroll
    for (int r = 0; r < 4; ++r) mx[r] = fmaxf(sc[0][r], sc[1][r]);
#pragma unroll
    for (int off = 1; off < 16; off <<= 1)
#pragma unroll
      for (int r = 0; r < 4; ++r) mx[r] = fmaxf(mx[r], __shfl_xor(mx[r], off));
    float al[4];
#pragma unroll
    for (int r = 0; r < 4; ++r) {
      float mn = fmaxf(mrow[r], mx[r]);  // tile 0 always has valid keys: mn finite
      al[r] = __expf(mrow[r] - mn);
      mrow[r] = mn;
    }
    float p[2][4];
#pragma unroll
    for (int g = 0; g < 2; ++g)
#pragma unroll
      for (int r = 0; r < 4; ++r) p[g][r] = __expf(sc[g][r] - mrow[r]);  // masked -> 0
    float rs[4];
#pragma unroll
    for (int r = 0; r < 4; ++r) rs[r] = p[0][r] + p[1][r];
#pragma unroll
    for (int off = 1; off < 16; off <<= 1)
#pragma unroll
      for (int r = 0; r < 4; ++r) rs[r] += __shfl_xor(rs[r], off);
#pragma unroll
    for (int r = 0; r < 4; ++r) lrow[r] = lrow[r] * al[r] + rs[r];
#pragma unroll
    for (int g4 = 0; g4 < 4; ++g4)
#pragma unroll
      for (int r = 0; r < 4; ++r) o[g4][r] *= al[r];
    // ---- P: C-layout -> LDS -> A-layout (wave-local; compiler inserts lgkmcnt) ----
#pragma unroll
    for (int g = 0; g < 2; ++g)
#pragma unroll
      for (int r = 0; r < 4; ++r)
        Ps[wave][quad * 4 + r][g * 16 + l16] = f2bf(p[g][r]);
    bf16x8 pa = *(const bf16x8*)&Ps[wave][l16][quad * 8];
    // ---- O += P V ----
#pragma unroll
    for (int g4 = 0; g4 < 4; ++g4) {
      bf16x8 vf;  // B-frag: n=l16 (dim), k=quad*8+j (key)
#pragma unroll
      for (int j = 0; j < 8; ++j) vf[j] = (short)Vs[quad * 8 + j][g4 * 16 + l16];
      o[g4] = __builtin_amdgcn_mfma_f32_16x16x32_bf16(pa, vf, o[g4], 0, 0, 0);
    }
  }
  // ---- epilogue: normalize, store ctx bf16 [4096][1024] ----
#pragma unroll
  for (int r = 0; r < 4; ++r) {
    float inv = 1.0f / lrow[r];
    size_t row = (size_t)(b * 2048 + q0 + quad * 4 + r) * 1024 + h * 64;
#pragma unroll
    for (int g4 = 0; g4 < 4; ++g4)
      ctx[row + g4 * 16 + l16] = f2bf(o[g4][r] * inv);
  }
}

// ---------------- launch ----------------
extern "C" void kernel_launch(void* const* d_in, const int* in_sizes, int n_in,
                              void* d_out, int out_size, void* d_ws, size_t ws_size,
                              hipStream_t stream) {
  const float* x  = (const float*)d_in[0];
  const float* Wq = (const float*)d_in[1];
  const float* Wk = (const float*)d_in[2];
  const float* Wv = (const float*)d_in[3];
  const float* Wo = (const float*)d_in[4];
  const float* bo = (const float*)d_in[5];
  float* out = (float*)d_out;

  // workspace layout (48 MB total)
  char* ws = (char*)d_ws;
  unsigned short* Xb    = (unsigned short*)(ws);                      //  8 MB: x bf16 [4096][1024]
  unsigned short* Wqkvt = (unsigned short*)(ws + (size_t)8  * 1048576);  //  6 MB: [3072][1024]
  unsigned short* Wot   = (unsigned short*)(ws + (size_t)14 * 1048576);  //  2 MB: [1024][1024]
  unsigned short* QKV   = (unsigned short*)(ws + (size_t)16 * 1048576);  // 24 MB: [4096][3072]
  unsigned short* CT    = (unsigned short*)(ws + (size_t)40 * 1048576);  //  8 MB: [4096][1024]

  cast_kernel<<<4096, 256, 0, stream>>>(x, Xb, 1048576);
  transpose_cast<<<dim3(32, 32, 4), 256, 0, stream>>>(Wq, Wk, Wv, Wo, Wqkvt, Wot);
  gemm_bt<1, 0><<<dim3(24, 32), 256, 0, stream>>>(Xb, Wqkvt, QKV, nullptr, 4096, 3072, 1024);
  attn_kernel<<<dim3(32, 32), 256, 0, stream>>>(QKV, CT);
  gemm_bt<0, 1><<<dim3(8, 32), 256, 0, stream>>>(CT, Wot, out, bo, 4096, 1024, 1024);
}

// Round 2
// 317.068 us; speedup vs baseline: 1.0940x; 1.0940x over previous
//
#include <hip/hip_runtime.h>
#include <hip/hip_bf16.h>
#include <math.h>

typedef __attribute__((ext_vector_type(8))) short bf16x8;
typedef __attribute__((ext_vector_type(8))) unsigned short u16x8;
typedef __attribute__((ext_vector_type(4))) float f32x4;

__device__ __forceinline__ unsigned short f2bf(float f) {
  union { float f; unsigned u; } c; c.f = f;
  unsigned u = c.u;
  u += 0x7fffu + ((u >> 16) & 1u);   // round-to-nearest-even
  return (unsigned short)(u >> 16);
}
__device__ __forceinline__ unsigned fb(float x) {
  union { float f; unsigned u; } c; c.f = x; return c.u;
}
// async global->LDS, 16B per lane; LDS dest must be wave-uniform base + lane*16
__device__ __forceinline__ void async16(const unsigned short* g, unsigned short* l) {
  __builtin_amdgcn_global_load_lds(
      (const __attribute__((address_space(1))) unsigned int*)g,
      (__attribute__((address_space(3))) unsigned int*)l, 16, 0, 0);
}

// ---------------- cast fp32 -> bf16 (vectorized) ----------------
__global__ __launch_bounds__(256) void cast_kernel(const float* __restrict__ in,
                                                   unsigned short* __restrict__ out,
                                                   int n4) {
  int i = blockIdx.x * 256 + threadIdx.x;
  if (i >= n4) return;
  float4 v = ((const float4*)in)[i];
  ushort4 o;
  o.x = f2bf(v.x); o.y = f2bf(v.y); o.z = f2bf(v.z); o.w = f2bf(v.w);
  ((ushort4*)out)[i] = o;
}

// ------------- transpose+cast 1024x1024 fp32 -> bf16 (N x K) -------------
__global__ __launch_bounds__(256) void transpose_cast(
    const float* __restrict__ Wq, const float* __restrict__ Wk,
    const float* __restrict__ Wv, const float* __restrict__ Wo,
    unsigned short* __restrict__ Wqkvt, unsigned short* __restrict__ Wot) {
  __shared__ float t[32][33];
  int z = blockIdx.z;
  const float* src = (z == 0) ? Wq : (z == 1) ? Wk : (z == 2) ? Wv : Wo;
  unsigned short* dst = (z < 3) ? (Wqkvt + (size_t)z * 1024 * 1024) : Wot;
  int tx = threadIdx.x & 31, ty = threadIdx.x >> 5;
  int bx = blockIdx.x, by = blockIdx.y;
#pragma unroll
  for (int i = 0; i < 4; ++i)
    t[ty + i * 8][tx] = src[(size_t)(by * 32 + ty + i * 8) * 1024 + bx * 32 + tx];
  __syncthreads();
#pragma unroll
  for (int i = 0; i < 4; ++i)
    dst[(size_t)(bx * 32 + ty + i * 8) * 1024 + by * 32 + tx] = f2bf(t[tx][ty + i * 8]);
}

// ---------------- bf16 GEMM: C = A[M][K] * Bt[N][K]^T ----------------
// MODE 0: fp32 out + bias. MODE 1: cols<2048 -> bf16 QK[token][2048];
//         cols>=2048 -> V transposed into Vt[b*16+h][d][s] (bf16).
// 128x128 tile, BK=32, 4 waves (2x2 of 64x64), global_load_lds staging (m97).
template <int MODE>
__global__ __launch_bounds__(256) void gemm_bt(
    const unsigned short* __restrict__ A, const unsigned short* __restrict__ Bt,
    void* __restrict__ Cout, unsigned short* __restrict__ Vt,
    const float* __restrict__ bias, int M, int N, int K) {
  __shared__ unsigned short As[128][32];  // unpadded: global_load_lds lane ordering
  __shared__ unsigned short Bs[128][32];
  const int tid = threadIdx.x;
  const int wave = tid >> 6, lane = tid & 63;
  const int quad = lane >> 4, l16 = lane & 15;
  const int m0 = blockIdx.y * 128, n0 = blockIdx.x * 128;
  const int wm = (wave >> 1) * 64, wn = (wave & 1) * 64;
  const int srow = tid >> 2, sch = (tid & 3) * 8;  // LDS byte addr = tid*16
  f32x4 acc[4][4] = {};

  for (int k0 = 0; k0 < K; k0 += 32) {
    __syncthreads();
    async16(A  + (size_t)(m0 + srow) * K + k0 + sch, &As[srow][sch]);
    async16(Bt + (size_t)(n0 + srow) * K + k0 + sch, &Bs[srow][sch]);
    async16(A  + (size_t)(m0 + srow + 64) * K + k0 + sch, &As[srow + 64][sch]);
    async16(Bt + (size_t)(n0 + srow + 64) * K + k0 + sch, &Bs[srow + 64][sch]);
    __syncthreads();
    bf16x8 af[4], bfr[4];
#pragma unroll
    for (int i = 0; i < 4; ++i) {
      af[i]  = *(const bf16x8*)&As[wm + i * 16 + l16][quad * 8];
      bfr[i] = *(const bf16x8*)&Bs[wn + i * 16 + l16][quad * 8];
    }
#pragma unroll
    for (int mi = 0; mi < 4; ++mi)
#pragma unroll
      for (int ni = 0; ni < 4; ++ni)
        acc[mi][ni] = __builtin_amdgcn_mfma_f32_16x16x32_bf16(af[mi], bfr[ni], acc[mi][ni], 0, 0, 0);
  }

#pragma unroll
  for (int mi = 0; mi < 4; ++mi) {
#pragma unroll
    for (int ni = 0; ni < 4; ++ni) {
      const int col = n0 + wn + ni * 16 + l16;
      const int token0 = m0 + wm + mi * 16 + quad * 4;  // r=0..3 consecutive tokens
      if (MODE == 0) {
        float bv = bias[col];
        float* C = (float*)Cout;
#pragma unroll
        for (int r = 0; r < 4; ++r)
          C[(size_t)(token0 + r) * N + col] = acc[mi][ni][r] + bv;
      } else {
        if (col < 2048) {
          unsigned short* QK = (unsigned short*)Cout;
#pragma unroll
          for (int r = 0; r < 4; ++r)
            QK[(size_t)(token0 + r) * 2048 + col] = f2bf(acc[mi][ni][r]);
        } else {
          const int vc = col - 2048, hh = vc >> 6, d = vc & 63;
          const int bb = token0 >> 11, s0 = token0 & 2047;
          ushort4 us;
          us.x = f2bf(acc[mi][ni][0]); us.y = f2bf(acc[mi][ni][1]);
          us.z = f2bf(acc[mi][ni][2]); us.w = f2bf(acc[mi][ni][3]);
          *(ushort4*)&Vt[(((size_t)bb * 16 + hh) * 64 + d) * 2048 + s0] = us;
        }
      }
    }
  }
}

// ---------------- causal flash attention (S^T formulation) ----------------
// QK: [4096][2048] bf16 rows = [q(1024)|k(1024)]. Vt: [32][64][2048] bf16.
// grid (S/128, B*H), 4 waves/block, 32 queries/wave, 32-key tiles, no barriers.
// S^T = K(A) * Q(B): C-layout row=key(quad*4+r), col=query(l16) -> key
// reductions are in-register + 2 shfl steps. O^T = Vt(A) * P^T(B).
__global__ __launch_bounds__(256) void attn_kernel(
    const unsigned short* __restrict__ QK, const unsigned short* __restrict__ Vt,
    unsigned short* __restrict__ ctx) {
  const int b = blockIdx.y >> 4, h = blockIdx.y & 15;
  const int wave = threadIdx.x >> 6, lane = threadIdx.x & 63;
  const int quad = lane >> 4, l16 = lane & 15;
  const int qw0 = blockIdx.x * 128 + wave * 32;
  const unsigned short* Qp = QK + (size_t)b * 2048 * 2048 + h * 64;
  const unsigned short* Kp = Qp + 1024;
  const unsigned short* Vp = Vt + (size_t)(b * 16 + h) * 64 * 2048;
  __shared__ unsigned short Pt[4][32][40];  // per-wave P^T roundtrip; 80B rows (16B-aligned)

  bf16x8 qf[2][2];  // B-frag: n=query(l16), k=dim(quad*8+j); [qg][kk]
#pragma unroll
  for (int qg = 0; qg < 2; ++qg)
#pragma unroll
    for (int kk = 0; kk < 2; ++kk)
      qf[qg][kk] = *(const bf16x8*)(Qp + (size_t)(qw0 + qg * 16 + l16) * 2048 + kk * 32 + quad * 8);

  f32x4 o[4][2] = {};                 // O^T: [dg][qg], row=d, col=q
  float m_[2] = {-INFINITY, -INFINITY}, l_[2] = {0.f, 0.f};
  const float C = 0.18033688f;        // (1/sqrt(64)) * log2(e)

  const int ntiles = (qw0 >> 5) + 1;
  for (int kt = 0; kt < ntiles; ++kt) {
    const int k0 = kt * 32;
    // ---- S^T = K Q^T ----
    f32x4 st[2][2] = {};  // [keyg][qg]
#pragma unroll
    for (int keyg = 0; keyg < 2; ++keyg)
#pragma unroll
      for (int kk = 0; kk < 2; ++kk) {
        bf16x8 kf = *(const bf16x8*)(Kp + (size_t)(k0 + keyg * 16 + l16) * 2048 + kk * 32 + quad * 8);
#pragma unroll
        for (int qg = 0; qg < 2; ++qg)
          st[keyg][qg] = __builtin_amdgcn_mfma_f32_16x16x32_bf16(kf, qf[qg][kk], st[keyg][qg], 0, 0, 0);
      }
    // ---- causal mask: only the diagonal tile needs it ----
    if (kt == ntiles - 1) {
#pragma unroll
      for (int keyg = 0; keyg < 2; ++keyg)
#pragma unroll
        for (int r = 0; r < 4; ++r) {
          const int key = k0 + keyg * 16 + quad * 4 + r;
#pragma unroll
          for (int qg = 0; qg < 2; ++qg)
            if (key > qw0 + qg * 16 + l16) st[keyg][qg][r] = -INFINITY;
        }
    }
    // ---- online softmax (keys in-register + 2 shfl steps over quads) ----
    float al[2];
#pragma unroll
    for (int qg = 0; qg < 2; ++qg) {
      float mx = st[0][qg][0];
#pragma unroll
      for (int r = 1; r < 4; ++r) mx = fmaxf(mx, st[0][qg][r]);
#pragma unroll
      for (int r = 0; r < 4; ++r) mx = fmaxf(mx, st[1][qg][r]);
      mx = fmaxf(mx, __shfl_xor(mx, 16));
      mx = fmaxf(mx, __shfl_xor(mx, 32));
      const float mn = fmaxf(m_[qg], mx * C);
      al[qg] = exp2f(m_[qg] - mn);
      m_[qg] = mn;
      float rs = 0.f;
#pragma unroll
      for (int keyg = 0; keyg < 2; ++keyg) {
        float p0 = exp2f(fmaf(st[keyg][qg][0], C, -mn));
        float p1 = exp2f(fmaf(st[keyg][qg][1], C, -mn));
        float p2 = exp2f(fmaf(st[keyg][qg][2], C, -mn));
        float p3 = exp2f(fmaf(st[keyg][qg][3], C, -mn));
        rs += (p0 + p1) + (p2 + p3);
        uint2 pk;  // truncate-to-bf16 pack via v_perm (values in [0,1])
        pk.x = __builtin_amdgcn_perm(fb(p1), fb(p0), 0x07060302u);
        pk.y = __builtin_amdgcn_perm(fb(p3), fb(p2), 0x07060302u);
        *(uint2*)&Pt[wave][qg * 16 + l16][keyg * 16 + quad * 4] = pk;
      }
      rs += __shfl_xor(rs, 16);
      rs += __shfl_xor(rs, 32);
      l_[qg] = l_[qg] * al[qg] + rs;
    }
    // ---- rescale O, then O^T += V^T P ----
#pragma unroll
    for (int dg = 0; dg < 4; ++dg)
#pragma unroll
      for (int qg = 0; qg < 2; ++qg)
#pragma unroll
        for (int r = 0; r < 4; ++r) o[dg][qg][r] *= al[qg];
    bf16x8 pb[2];  // B-frag: n=q(l16), k=key(quad*8+j) — wave-local LDS, no barrier
#pragma unroll
    for (int qg = 0; qg < 2; ++qg)
      pb[qg] = *(const bf16x8*)&Pt[wave][qg * 16 + l16][quad * 8];
#pragma unroll
    for (int dg = 0; dg < 4; ++dg) {
      bf16x8 vf = *(const bf16x8*)(Vp + (size_t)(dg * 16 + l16) * 2048 + k0 + quad * 8);
#pragma unroll
      for (int qg = 0; qg < 2; ++qg)
        o[dg][qg] = __builtin_amdgcn_mfma_f32_16x16x32_bf16(vf, pb[qg], o[dg][qg], 0, 0, 0);
    }
  }
  // ---- epilogue: normalize, store ctx bf16 [4096][1024] ----
#pragma unroll
  for (int qg = 0; qg < 2; ++qg) {
    const float inv = 1.f / l_[qg];
    const size_t base = (size_t)(b * 2048 + qw0 + qg * 16 + l16) * 1024 + h * 64;
#pragma unroll
    for (int dg = 0; dg < 4; ++dg) {
      ushort4 us;
      us.x = f2bf(o[dg][qg][0] * inv); us.y = f2bf(o[dg][qg][1] * inv);
      us.z = f2bf(o[dg][qg][2] * inv); us.w = f2bf(o[dg][qg][3] * inv);
      *(ushort4*)&ctx[base + dg * 16 + quad * 4] = us;
    }
  }
}

// ---------------- launch ----------------
extern "C" void kernel_launch(void* const* d_in, const int* in_sizes, int n_in,
                              void* d_out, int out_size, void* d_ws, size_t ws_size,
                              hipStream_t stream) {
  const float* x  = (const float*)d_in[0];
  const float* Wq = (const float*)d_in[1];
  const float* Wk = (const float*)d_in[2];
  const float* Wv = (const float*)d_in[3];
  const float* Wo = (const float*)d_in[4];
  const float* bo = (const float*)d_in[5];
  float* out = (float*)d_out;

  // workspace layout (48 MB total)
  char* ws = (char*)d_ws;
  unsigned short* Xb    = (unsigned short*)(ws);                          //  8 MB [4096][1024]
  unsigned short* Wqkvt = (unsigned short*)(ws + (size_t)8  * 1048576);   //  6 MB [3072][1024]
  unsigned short* Wot   = (unsigned short*)(ws + (size_t)14 * 1048576);   //  2 MB [1024][1024]
  unsigned short* QKb   = (unsigned short*)(ws + (size_t)16 * 1048576);   // 16 MB [4096][2048]
  unsigned short* Vt    = (unsigned short*)(ws + (size_t)32 * 1048576);   //  8 MB [32][64][2048]
  unsigned short* CT    = (unsigned short*)(ws + (size_t)40 * 1048576);   //  8 MB [4096][1024]

  cast_kernel<<<4096, 256, 0, stream>>>(x, Xb, 1048576);
  transpose_cast<<<dim3(32, 32, 4), 256, 0, stream>>>(Wq, Wk, Wv, Wo, Wqkvt, Wot);
  gemm_bt<1><<<dim3(24, 32), 256, 0, stream>>>(Xb, Wqkvt, QKb, Vt, nullptr, 4096, 3072, 1024);
  attn_kernel<<<dim3(16, 32), 256, 0, stream>>>(QKb, Vt, CT);
  gemm_bt<0><<<dim3(8, 32), 256, 0, stream>>>(CT, Wot, out, nullptr, bo, 4096, 1024, 1024);
}

// Round 3
// 246.073 us; speedup vs baseline: 1.4096x; 1.2885x over previous
//
#include <hip/hip_runtime.h>
#include <hip/hip_bf16.h>
#include <math.h>

typedef __attribute__((ext_vector_type(8))) short bf16x8;
typedef __attribute__((ext_vector_type(8))) unsigned short u16x8;
typedef __attribute__((ext_vector_type(4))) float f32x4;

__device__ __forceinline__ unsigned short f2bf(float f) {
  union { float f; unsigned u; } c; c.f = f;
  unsigned u = c.u;
  u += 0x7fffu + ((u >> 16) & 1u);   // round-to-nearest-even
  return (unsigned short)(u >> 16);
}
__device__ __forceinline__ unsigned fb(float x) {
  union { float f; unsigned u; } c; c.f = x; return c.u;
}
// async global->LDS, 16B per lane; LDS dest must be wave-uniform base + lane*16
__device__ __forceinline__ void async16(const unsigned short* g, unsigned short* l) {
  __builtin_amdgcn_global_load_lds(
      (const __attribute__((address_space(1))) unsigned int*)g,
      (__attribute__((address_space(3))) unsigned int*)l, 16, 0, 0);
}

// ---------------- cast fp32 -> bf16 (vectorized) ----------------
__global__ __launch_bounds__(256) void cast_kernel(const float* __restrict__ in,
                                                   unsigned short* __restrict__ out,
                                                   int n4) {
  int i = blockIdx.x * 256 + threadIdx.x;
  if (i >= n4) return;
  float4 v = ((const float4*)in)[i];
  ushort4 o;
  o.x = f2bf(v.x); o.y = f2bf(v.y); o.z = f2bf(v.z); o.w = f2bf(v.w);
  ((ushort4*)out)[i] = o;
}

// ------------- transpose+cast 1024x1024 fp32 -> bf16 (N x K) -------------
__global__ __launch_bounds__(256) void transpose_cast(
    const float* __restrict__ Wq, const float* __restrict__ Wk,
    const float* __restrict__ Wv, const float* __restrict__ Wo,
    unsigned short* __restrict__ Wqkvt, unsigned short* __restrict__ Wot) {
  __shared__ float t[32][33];
  int z = blockIdx.z;
  const float* src = (z == 0) ? Wq : (z == 1) ? Wk : (z == 2) ? Wv : Wo;
  unsigned short* dst = (z < 3) ? (Wqkvt + (size_t)z * 1024 * 1024) : Wot;
  int tx = threadIdx.x & 31, ty = threadIdx.x >> 5;
  int bx = blockIdx.x, by = blockIdx.y;
#pragma unroll
  for (int i = 0; i < 4; ++i)
    t[ty + i * 8][tx] = src[(size_t)(by * 32 + ty + i * 8) * 1024 + bx * 32 + tx];
  __syncthreads();
#pragma unroll
  for (int i = 0; i < 4; ++i)
    dst[(size_t)(bx * 32 + ty + i * 8) * 1024 + by * 32 + tx] = f2bf(t[tx][ty + i * 8]);
}

// ---------------- bf16 GEMM: C = A[M][K] * Bt[N][K]^T ----------------
// MODE 0: fp32 out + bias.
// MODE 1: col<1024 -> Qh[bh][s][64]; col<2048 -> Kh[bh][s][64];
//         col>=2048 -> tiled Vt[bh][s>>5][d][32]  (all bf16, head-major)
template <int MODE>
__global__ __launch_bounds__(256) void gemm_bt(
    const unsigned short* __restrict__ A, const unsigned short* __restrict__ Bt,
    void* __restrict__ Cout, unsigned short* __restrict__ Kh,
    unsigned short* __restrict__ Vt, const float* __restrict__ bias,
    int M, int N, int K) {
  __shared__ unsigned short As[128][32];  // unpadded: global_load_lds lane ordering
  __shared__ unsigned short Bs[128][32];
  const int tid = threadIdx.x;
  const int wave = tid >> 6, lane = tid & 63;
  const int quad = lane >> 4, l16 = lane & 15;
  const int m0 = blockIdx.y * 128, n0 = blockIdx.x * 128;
  const int wm = (wave >> 1) * 64, wn = (wave & 1) * 64;
  const int srow = tid >> 2, sch = (tid & 3) * 8;  // LDS byte addr = tid*16
  f32x4 acc[4][4] = {};

  for (int k0 = 0; k0 < K; k0 += 32) {
    __syncthreads();
    async16(A  + (size_t)(m0 + srow) * K + k0 + sch, &As[srow][sch]);
    async16(Bt + (size_t)(n0 + srow) * K + k0 + sch, &Bs[srow][sch]);
    async16(A  + (size_t)(m0 + srow + 64) * K + k0 + sch, &As[srow + 64][sch]);
    async16(Bt + (size_t)(n0 + srow + 64) * K + k0 + sch, &Bs[srow + 64][sch]);
    __syncthreads();
    bf16x8 af[4], bfr[4];
#pragma unroll
    for (int i = 0; i < 4; ++i) {
      af[i]  = *(const bf16x8*)&As[wm + i * 16 + l16][quad * 8];
      bfr[i] = *(const bf16x8*)&Bs[wn + i * 16 + l16][quad * 8];
    }
#pragma unroll
    for (int mi = 0; mi < 4; ++mi)
#pragma unroll
      for (int ni = 0; ni < 4; ++ni)
        acc[mi][ni] = __builtin_amdgcn_mfma_f32_16x16x32_bf16(af[mi], bfr[ni], acc[mi][ni], 0, 0, 0);
  }

#pragma unroll
  for (int mi = 0; mi < 4; ++mi) {
#pragma unroll
    for (int ni = 0; ni < 4; ++ni) {
      const int col = n0 + wn + ni * 16 + l16;
      const int token0 = m0 + wm + mi * 16 + quad * 4;  // r=0..3 consecutive tokens
      if (MODE == 0) {
        float bv = bias[col];
        float* C = (float*)Cout;
#pragma unroll
        for (int r = 0; r < 4; ++r)
          C[(size_t)(token0 + r) * N + col] = acc[mi][ni][r] + bv;
      } else {
        const int bb = token0 >> 11, s0 = token0 & 2047;
        if (col < 2048) {  // Q or K, head-major [bh][s][64]
          const int hh = (col & 1023) >> 6, d = col & 63;
          unsigned short* dst = (col < 1024) ? (unsigned short*)Cout : Kh;
          dst += ((size_t)(bb * 16 + hh) * 2048 + s0) * 64 + d;
#pragma unroll
          for (int r = 0; r < 4; ++r) dst[(size_t)r * 64] = f2bf(acc[mi][ni][r]);
        } else {           // V, tiled [bh][s>>5][d][32]
          const int vc = col - 2048, hh = vc >> 6, d = vc & 63;
          ushort4 us;
          us.x = f2bf(acc[mi][ni][0]); us.y = f2bf(acc[mi][ni][1]);
          us.z = f2bf(acc[mi][ni][2]); us.w = f2bf(acc[mi][ni][3]);
          *(ushort4*)&Vt[(((size_t)(bb * 16 + hh) * 64 + (s0 >> 5)) * 64 + d) * 32 + (s0 & 31)] = us;
        }
      }
    }
  }
}

// ---------------- causal flash attention, LDS-staged K/V ----------------
// Qh,Kh: [32 bh][2048][64] bf16. Vt: [32 bh][64 kt][64 d][32 s] bf16.
// grid (16, 32): blockIdx.x = pair a -> strips (a, 31-a) of 64 queries.
// 4 waves: w0,w1 -> strip a (32 q each); w2,w3 -> strip 31-a. Balanced:
// every block computes exactly 130 tile-iters. K/V tiles (contiguous 4KB)
// are register-prefetched and staged in LDS, shared by all 4 waves.
__global__ __launch_bounds__(256) void attn_kernel(
    const unsigned short* __restrict__ Qh, const unsigned short* __restrict__ Kh,
    const unsigned short* __restrict__ Vt, unsigned short* __restrict__ ctx) {
  const int a = blockIdx.x, bh = blockIdx.y;
  const int b = bh >> 4, h = bh & 15;
  const int tid = threadIdx.x;
  const int wave = tid >> 6, lane = tid & 63;
  const int quad = lane >> 4, l16 = lane & 15;
  const int strip = (wave < 2) ? a : (31 - a);
  const int q0 = strip * 64 + (wave & 1) * 32;
  const int my_ntiles = (q0 >> 5) + 1;
  const int ktmax = 64 - 2 * a;

  __shared__ unsigned short Ks[32][72];   // 32 keys x 64 dims (+pad)
  __shared__ unsigned short Vs[64][40];   // 64 dims x 32 keys (+pad)
  __shared__ unsigned short Pt[4][32][40];

  const unsigned short* Qp  = Qh + (size_t)bh * 2048 * 64;
  const unsigned short* Kg  = Kh + (size_t)bh * 2048 * 64;   // tile kt at +kt*2048
  const unsigned short* Vg  = Vt + (size_t)bh * 64 * 2048;   // tile kt at +kt*2048

  bf16x8 qf[2][2];  // B-frag: n=query(l16), k=dim(quad*8+j); [qg][kk]
#pragma unroll
  for (int qg = 0; qg < 2; ++qg)
#pragma unroll
    for (int kk = 0; kk < 2; ++kk)
      qf[qg][kk] = *(const bf16x8*)(Qp + (size_t)(q0 + qg * 16 + l16) * 64 + kk * 32 + quad * 8);

  f32x4 o[4][2] = {};                 // O^T: [dg][qg]
  float m_[2] = {-INFINITY, -INFINITY}, l_[2] = {0.f, 0.f};
  const float C = 0.18033688f;        // (1/sqrt(64)) * log2(e)

  // staging indices (thread -> 16B chunk of the 4KB tile)
  const int kr = tid >> 3, kc = (tid & 7) * 8;   // K: key row, chunk
  const int vr = tid >> 2, vc = (tid & 3) * 8;   // V: dim row, chunk

  u16x8 kreg = *(const u16x8*)(Kg + tid * 8);
  u16x8 vreg = *(const u16x8*)(Vg + tid * 8);

  for (int kt = 0; kt < ktmax; ++kt) {
    __syncthreads();                       // LDS readers of tile kt-1 done
    *(u16x8*)&Ks[kr][kc] = kreg;
    *(u16x8*)&Vs[vr][vc] = vreg;
    __syncthreads();                       // tile kt staged
    if (kt + 1 < ktmax) {                  // prefetch kt+1 (vmcnt waited next iter)
      kreg = *(const u16x8*)(Kg + (size_t)(kt + 1) * 2048 + tid * 8);
      vreg = *(const u16x8*)(Vg + (size_t)(kt + 1) * 2048 + tid * 8);
    }
    if (kt >= my_ntiles) continue;         // wave-uniform; barriers stay aligned
    const int k0 = kt * 32;
    // ---- S^T = K Q^T ----
    f32x4 st[2][2] = {};  // [keyg][qg]
#pragma unroll
    for (int keyg = 0; keyg < 2; ++keyg)
#pragma unroll
      for (int kk = 0; kk < 2; ++kk) {
        bf16x8 kf = *(const bf16x8*)&Ks[keyg * 16 + l16][kk * 32 + quad * 8];
#pragma unroll
        for (int qg = 0; qg < 2; ++qg)
          st[keyg][qg] = __builtin_amdgcn_mfma_f32_16x16x32_bf16(kf, qf[qg][kk], st[keyg][qg], 0, 0, 0);
      }
    // ---- causal mask: only the diagonal tile ----
    if (kt == my_ntiles - 1) {
#pragma unroll
      for (int keyg = 0; keyg < 2; ++keyg)
#pragma unroll
        for (int r = 0; r < 4; ++r) {
          const int key = k0 + keyg * 16 + quad * 4 + r;
#pragma unroll
          for (int qg = 0; qg < 2; ++qg)
            if (key > q0 + qg * 16 + l16) st[keyg][qg][r] = -INFINITY;
        }
    }
    // ---- online softmax (keys in-register + 2 shfl steps) ----
    float al[2];
#pragma unroll
    for (int qg = 0; qg < 2; ++qg) {
      float mx = st[0][qg][0];
#pragma unroll
      for (int r = 1; r < 4; ++r) mx = fmaxf(mx, st[0][qg][r]);
#pragma unroll
      for (int r = 0; r < 4; ++r) mx = fmaxf(mx, st[1][qg][r]);
      mx = fmaxf(mx, __shfl_xor(mx, 16));
      mx = fmaxf(mx, __shfl_xor(mx, 32));
      const float mn = fmaxf(m_[qg], mx * C);
      al[qg] = exp2f(m_[qg] - mn);
      m_[qg] = mn;
      float rs = 0.f;
#pragma unroll
      for (int keyg = 0; keyg < 2; ++keyg) {
        float p0 = exp2f(fmaf(st[keyg][qg][0], C, -mn));
        float p1 = exp2f(fmaf(st[keyg][qg][1], C, -mn));
        float p2 = exp2f(fmaf(st[keyg][qg][2], C, -mn));
        float p3 = exp2f(fmaf(st[keyg][qg][3], C, -mn));
        rs += (p0 + p1) + (p2 + p3);
        uint2 pk;  // truncate-to-bf16 pack via v_perm (values in [0,1])
        pk.x = __builtin_amdgcn_perm(fb(p1), fb(p0), 0x07060302u);
        pk.y = __builtin_amdgcn_perm(fb(p3), fb(p2), 0x07060302u);
        *(uint2*)&Pt[wave][qg * 16 + l16][keyg * 16 + quad * 4] = pk;
      }
      rs += __shfl_xor(rs, 16);
      rs += __shfl_xor(rs, 32);
      l_[qg] = l_[qg] * al[qg] + rs;
    }
    // ---- rescale O, then O^T += V^T P ----
#pragma unroll
    for (int dg = 0; dg < 4; ++dg)
#pragma unroll
      for (int qg = 0; qg < 2; ++qg)
#pragma unroll
        for (int r = 0; r < 4; ++r) o[dg][qg][r] *= al[qg];
    bf16x8 pb[2];  // B-frag: n=q(l16), k=key(quad*8+j) — wave-local LDS
#pragma unroll
    for (int qg = 0; qg < 2; ++qg)
      pb[qg] = *(const bf16x8*)&Pt[wave][qg * 16 + l16][quad * 8];
#pragma unroll
    for (int dg = 0; dg < 4; ++dg) {
      bf16x8 vf = *(const bf16x8*)&Vs[dg * 16 + l16][quad * 8];  // A-frag V^T
#pragma unroll
      for (int qg = 0; qg < 2; ++qg)
        o[dg][qg] = __builtin_amdgcn_mfma_f32_16x16x32_bf16(vf, pb[qg], o[dg][qg], 0, 0, 0);
    }
  }
  // ---- epilogue: normalize, store ctx bf16 [4096][1024] ----
#pragma unroll
  for (int qg = 0; qg < 2; ++qg) {
    const float inv = 1.f / l_[qg];
    const size_t base = (size_t)(b * 2048 + q0 + qg * 16 + l16) * 1024 + h * 64;
#pragma unroll
    for (int dg = 0; dg < 4; ++dg) {
      ushort4 us;
      us.x = f2bf(o[dg][qg][0] * inv); us.y = f2bf(o[dg][qg][1] * inv);
      us.z = f2bf(o[dg][qg][2] * inv); us.w = f2bf(o[dg][qg][3] * inv);
      *(ushort4*)&ctx[base + dg * 16 + quad * 4] = us;
    }
  }
}

// ---------------- launch ----------------
extern "C" void kernel_launch(void* const* d_in, const int* in_sizes, int n_in,
                              void* d_out, int out_size, void* d_ws, size_t ws_size,
                              hipStream_t stream) {
  const float* x  = (const float*)d_in[0];
  const float* Wq = (const float*)d_in[1];
  const float* Wk = (const float*)d_in[2];
  const float* Wv = (const float*)d_in[3];
  const float* Wo = (const float*)d_in[4];
  const float* bo = (const float*)d_in[5];
  float* out = (float*)d_out;

  // workspace layout (48 MB total)
  char* ws = (char*)d_ws;
  unsigned short* Xb    = (unsigned short*)(ws);                          //  8 MB [4096][1024]
  unsigned short* Wqkvt = (unsigned short*)(ws + (size_t)8  * 1048576);   //  6 MB [3072][1024]
  unsigned short* Wot   = (unsigned short*)(ws + (size_t)14 * 1048576);   //  2 MB [1024][1024]
  unsigned short* Qhb   = (unsigned short*)(ws + (size_t)16 * 1048576);   //  8 MB [32][2048][64]
  unsigned short* Khb   = (unsigned short*)(ws + (size_t)24 * 1048576);   //  8 MB [32][2048][64]
  unsigned short* Vtb   = (unsigned short*)(ws + (size_t)32 * 1048576);   //  8 MB [32][64][64][32]
  unsigned short* CT    = (unsigned short*)(ws + (size_t)40 * 1048576);   //  8 MB [4096][1024]

  cast_kernel<<<4096, 256, 0, stream>>>(x, Xb, 1048576);
  transpose_cast<<<dim3(32, 32, 4), 256, 0, stream>>>(Wq, Wk, Wv, Wo, Wqkvt, Wot);
  gemm_bt<1><<<dim3(24, 32), 256, 0, stream>>>(Xb, Wqkvt, Qhb, Khb, Vtb, nullptr, 4096, 3072, 1024);
  attn_kernel<<<dim3(16, 32), 256, 0, stream>>>(Qhb, Khb, Vtb, CT);
  gemm_bt<0><<<dim3(8, 32), 256, 0, stream>>>(CT, Wot, out, nullptr, nullptr, bo, 4096, 1024, 1024);
}

// Round 4
// 226.625 us; speedup vs baseline: 1.5306x; 1.0858x over previous
//
#include <hip/hip_runtime.h>
#include <hip/hip_bf16.h>
#include <math.h>

typedef __attribute__((ext_vector_type(8))) short bf16x8;
typedef __attribute__((ext_vector_type(8))) unsigned short u16x8;
typedef __attribute__((ext_vector_type(4))) float f32x4;

__device__ __forceinline__ unsigned short f2bf(float f) {
  union { float f; unsigned u; } c; c.f = f;
  unsigned u = c.u;
  u += 0x7fffu + ((u >> 16) & 1u);   // round-to-nearest-even
  return (unsigned short)(u >> 16);
}
__device__ __forceinline__ unsigned fb(float x) {
  union { float f; unsigned u; } c; c.f = x; return c.u;
}
// async global->LDS, 16B per lane; LDS dest must be wave-uniform base + lane*16
__device__ __forceinline__ void async16(const unsigned short* g, unsigned short* l) {
  __builtin_amdgcn_global_load_lds(
      (const __attribute__((address_space(1))) unsigned int*)g,
      (__attribute__((address_space(3))) unsigned int*)l, 16, 0, 0);
}

// ---------------- cast fp32 -> bf16 (vectorized) ----------------
__global__ __launch_bounds__(256) void cast_kernel(const float* __restrict__ in,
                                                   unsigned short* __restrict__ out,
                                                   int n4) {
  int i = blockIdx.x * 256 + threadIdx.x;
  if (i >= n4) return;
  float4 v = ((const float4*)in)[i];
  ushort4 o;
  o.x = f2bf(v.x); o.y = f2bf(v.y); o.z = f2bf(v.z); o.w = f2bf(v.w);
  ((ushort4*)out)[i] = o;
}

// ------------- transpose+cast 1024x1024 fp32 -> bf16 (N x K) -------------
__global__ __launch_bounds__(256) void transpose_cast(
    const float* __restrict__ Wq, const float* __restrict__ Wk,
    const float* __restrict__ Wv, const float* __restrict__ Wo,
    unsigned short* __restrict__ Wqkvt, unsigned short* __restrict__ Wot) {
  __shared__ float t[32][33];
  int z = blockIdx.z;
  const float* src = (z == 0) ? Wq : (z == 1) ? Wk : (z == 2) ? Wv : Wo;
  unsigned short* dst = (z < 3) ? (Wqkvt + (size_t)z * 1024 * 1024) : Wot;
  int tx = threadIdx.x & 31, ty = threadIdx.x >> 5;
  int bx = blockIdx.x, by = blockIdx.y;
#pragma unroll
  for (int i = 0; i < 4; ++i)
    t[ty + i * 8][tx] = src[(size_t)(by * 32 + ty + i * 8) * 1024 + bx * 32 + tx];
  __syncthreads();
#pragma unroll
  for (int i = 0; i < 4; ++i)
    dst[(size_t)(bx * 32 + ty + i * 8) * 1024 + by * 32 + tx] = f2bf(t[tx][ty + i * 8]);
}

// ---------------- bf16 GEMM: C = A[M][K] * Bt[N][K]^T ----------------
// MODE 0: fp32 out + bias.
// MODE 1: col<1024 -> Qh[bh][s][64]; col<2048 -> Kh[bh][s][64];
//         col>=2048 -> tiled Vt[bh][s>>5][d][32]  (all bf16, head-major)
template <int MODE>
__global__ __launch_bounds__(256) void gemm_bt(
    const unsigned short* __restrict__ A, const unsigned short* __restrict__ Bt,
    void* __restrict__ Cout, unsigned short* __restrict__ Kh,
    unsigned short* __restrict__ Vt, const float* __restrict__ bias,
    int M, int N, int K) {
  __shared__ unsigned short As[128][32];  // unpadded: global_load_lds lane ordering
  __shared__ unsigned short Bs[128][32];
  const int tid = threadIdx.x;
  const int wave = tid >> 6, lane = tid & 63;
  const int quad = lane >> 4, l16 = lane & 15;
  const int m0 = blockIdx.y * 128, n0 = blockIdx.x * 128;
  const int wm = (wave >> 1) * 64, wn = (wave & 1) * 64;
  const int srow = tid >> 2, sch = (tid & 3) * 8;  // LDS byte addr = tid*16
  f32x4 acc[4][4] = {};

  for (int k0 = 0; k0 < K; k0 += 32) {
    __syncthreads();
    async16(A  + (size_t)(m0 + srow) * K + k0 + sch, &As[srow][sch]);
    async16(Bt + (size_t)(n0 + srow) * K + k0 + sch, &Bs[srow][sch]);
    async16(A  + (size_t)(m0 + srow + 64) * K + k0 + sch, &As[srow + 64][sch]);
    async16(Bt + (size_t)(n0 + srow + 64) * K + k0 + sch, &Bs[srow + 64][sch]);
    __syncthreads();
    bf16x8 af[4], bfr[4];
#pragma unroll
    for (int i = 0; i < 4; ++i) {
      af[i]  = *(const bf16x8*)&As[wm + i * 16 + l16][quad * 8];
      bfr[i] = *(const bf16x8*)&Bs[wn + i * 16 + l16][quad * 8];
    }
#pragma unroll
    for (int mi = 0; mi < 4; ++mi)
#pragma unroll
      for (int ni = 0; ni < 4; ++ni)
        acc[mi][ni] = __builtin_amdgcn_mfma_f32_16x16x32_bf16(af[mi], bfr[ni], acc[mi][ni], 0, 0, 0);
  }

#pragma unroll
  for (int mi = 0; mi < 4; ++mi) {
#pragma unroll
    for (int ni = 0; ni < 4; ++ni) {
      const int col = n0 + wn + ni * 16 + l16;
      const int token0 = m0 + wm + mi * 16 + quad * 4;  // r=0..3 consecutive tokens
      if (MODE == 0) {
        float bv = bias[col];
        float* C = (float*)Cout;
#pragma unroll
        for (int r = 0; r < 4; ++r)
          C[(size_t)(token0 + r) * N + col] = acc[mi][ni][r] + bv;
      } else {
        const int bb = token0 >> 11, s0 = token0 & 2047;
        if (col < 2048) {  // Q or K, head-major [bh][s][64]
          const int hh = (col & 1023) >> 6, d = col & 63;
          unsigned short* dst = (col < 1024) ? (unsigned short*)Cout : Kh;
          dst += ((size_t)(bb * 16 + hh) * 2048 + s0) * 64 + d;
#pragma unroll
          for (int r = 0; r < 4; ++r) dst[(size_t)r * 64] = f2bf(acc[mi][ni][r]);
        } else {           // V, tiled [bh][s>>5][d][32]
          const int vc = col - 2048, hh = vc >> 6, d = vc & 63;
          ushort4 us;
          us.x = f2bf(acc[mi][ni][0]); us.y = f2bf(acc[mi][ni][1]);
          us.z = f2bf(acc[mi][ni][2]); us.w = f2bf(acc[mi][ni][3]);
          *(ushort4*)&Vt[(((size_t)(bb * 16 + hh) * 64 + (s0 >> 5)) * 64 + d) * 32 + (s0 & 31)] = us;
        }
      }
    }
  }
}

// ---------------- causal flash attention, barrier-free ----------------
// Qh,Kh: [32 bh][2048][64] bf16. Vt: [32 bh][64 kt][64 d][32 s] bf16.
// grid (16, 32): blockIdx.x = pair a. 4 waves: w0,w1 -> strip a (32 q each),
// w2,w3 -> strip 31-a. Waves fully independent: K/V fragments load directly
// from global (head-major => contiguous 1-2KB per fragment load, L2-resident),
// K prefetched one tile ahead. LDS = per-wave P roundtrip only. Row-sum of P
// comes from a ones-row MFMA; O rescale is skipped (exactly) when no new max.
__global__ __launch_bounds__(256, 2) void attn_kernel(
    const unsigned short* __restrict__ Qh, const unsigned short* __restrict__ Kh,
    const unsigned short* __restrict__ Vt, unsigned short* __restrict__ ctx) {
  const int a = blockIdx.x, bh = blockIdx.y;
  const int b = bh >> 4, h = bh & 15;
  const int wave = threadIdx.x >> 6, lane = threadIdx.x & 63;
  const int quad = lane >> 4, l16 = lane & 15;
  const int strip = (wave < 2) ? a : (31 - a);
  const int q0 = strip * 64 + (wave & 1) * 32;
  const int ntiles = (q0 >> 5) + 1;

  __shared__ unsigned short Pt[4][32][40];  // per-wave P^T roundtrip

  const unsigned short* Qp = Qh + (size_t)bh * 2048 * 64;
  const unsigned short* Kg = Kh + (size_t)bh * 2048 * 64;
  const unsigned short* Vg = Vt + (size_t)bh * 64 * 2048;   // tile kt at +kt*2048

  bf16x8 qf[2][2];  // B-frag: n=query(l16), k=dim(quad*8+j); [qg][kk]
#pragma unroll
  for (int qg = 0; qg < 2; ++qg)
#pragma unroll
    for (int kk = 0; kk < 2; ++kk)
      qf[qg][kk] = *(const bf16x8*)(Qp + (size_t)(q0 + qg * 16 + l16) * 64 + kk * 32 + quad * 8);

  bf16x8 ones;  // A-frag of 1.0 rows: its PV output row = sum_k P = l
#pragma unroll
  for (int j = 0; j < 8; ++j) ones[j] = (short)0x3F80;

  f32x4 o[5][2] = {};                 // [dg 0..3]=O^T, [4]=l row; x [qg]
  float m_[2] = {-INFINITY, -INFINITY};
  const float C = 0.18033688f;        // (1/sqrt(64)) * log2(e)

  // K fragments for tile 0 (prefetch pattern)
  bf16x8 kfc[2][2], kfn[2][2];        // [keyg][kk]
#pragma unroll
  for (int keyg = 0; keyg < 2; ++keyg)
#pragma unroll
    for (int kk = 0; kk < 2; ++kk)
      kfc[keyg][kk] = *(const bf16x8*)(Kg + (size_t)(keyg * 16 + l16) * 64 + kk * 32 + quad * 8);

  for (int kt = 0; kt < ntiles; ++kt) {
    const int k0 = kt * 32;
    // ---- V fragments for this tile (needed only after softmax: self-hiding) ----
    bf16x8 vf[4];
#pragma unroll
    for (int dg = 0; dg < 4; ++dg)
      vf[dg] = *(const bf16x8*)(Vg + (size_t)kt * 2048 + (dg * 16 + l16) * 32 + quad * 8);
    // ---- prefetch next K tile ----
    if (kt + 1 < ntiles) {
#pragma unroll
      for (int keyg = 0; keyg < 2; ++keyg)
#pragma unroll
        for (int kk = 0; kk < 2; ++kk)
          kfn[keyg][kk] = *(const bf16x8*)(Kg + (size_t)(k0 + 32 + keyg * 16 + l16) * 64 + kk * 32 + quad * 8);
    }
    // ---- S^T = K Q^T ----
    f32x4 st[2][2] = {};  // [keyg][qg]
#pragma unroll
    for (int keyg = 0; keyg < 2; ++keyg)
#pragma unroll
      for (int kk = 0; kk < 2; ++kk)
#pragma unroll
        for (int qg = 0; qg < 2; ++qg)
          st[keyg][qg] = __builtin_amdgcn_mfma_f32_16x16x32_bf16(kfc[keyg][kk], qf[qg][kk], st[keyg][qg], 0, 0, 0);
#pragma unroll
    for (int keyg = 0; keyg < 2; ++keyg)
#pragma unroll
      for (int kk = 0; kk < 2; ++kk)
        kfc[keyg][kk] = kfn[keyg][kk];
    // ---- causal mask: only the diagonal tile ----
    if (kt == ntiles - 1) {
#pragma unroll
      for (int keyg = 0; keyg < 2; ++keyg)
#pragma unroll
        for (int r = 0; r < 4; ++r) {
          const int key = k0 + keyg * 16 + quad * 4 + r;
#pragma unroll
          for (int qg = 0; qg < 2; ++qg)
            if (key > q0 + qg * 16 + l16) st[keyg][qg][r] = -INFINITY;
        }
    }
    // ---- online softmax: max in-register + 2 shfl; sum via ones-row MFMA ----
    float al[2];
#pragma unroll
    for (int qg = 0; qg < 2; ++qg) {
      float mx = fmaxf(fmaxf(fmaxf(st[0][qg][0], st[0][qg][1]), fmaxf(st[0][qg][2], st[0][qg][3])),
                       fmaxf(fmaxf(st[1][qg][0], st[1][qg][1]), fmaxf(st[1][qg][2], st[1][qg][3])));
      mx = fmaxf(mx, __shfl_xor(mx, 16));
      mx = fmaxf(mx, __shfl_xor(mx, 32));
      const float mn = fmaxf(m_[qg], mx * C);
      al[qg] = exp2f(m_[qg] - mn);   // == 1.0 exactly when no new max
      m_[qg] = mn;
#pragma unroll
      for (int keyg = 0; keyg < 2; ++keyg) {
        float p0 = exp2f(fmaf(st[keyg][qg][0], C, -mn));
        float p1 = exp2f(fmaf(st[keyg][qg][1], C, -mn));
        float p2 = exp2f(fmaf(st[keyg][qg][2], C, -mn));
        float p3 = exp2f(fmaf(st[keyg][qg][3], C, -mn));
        uint2 pk;  // truncate-to-bf16 pack via v_perm (values in [0,1])
        pk.x = __builtin_amdgcn_perm(fb(p1), fb(p0), 0x07060302u);
        pk.y = __builtin_amdgcn_perm(fb(p3), fb(p2), 0x07060302u);
        *(uint2*)&Pt[wave][qg * 16 + l16][keyg * 16 + quad * 4] = pk;
      }
    }
    // ---- exact skip-rescale: only when some lane saw a new max ----
    if (__any(fminf(al[0], al[1]) < 1.0f)) {
#pragma unroll
      for (int dg = 0; dg < 5; ++dg)
#pragma unroll
        for (int qg = 0; qg < 2; ++qg)
#pragma unroll
          for (int r = 0; r < 4; ++r) o[dg][qg][r] *= al[qg];
    }
    // ---- O^T += V^T P ; l-row += 1^T P ----
    bf16x8 pb[2];  // B-frag: n=q(l16), k=key(quad*8+j) — wave-local LDS
#pragma unroll
    for (int qg = 0; qg < 2; ++qg)
      pb[qg] = *(const bf16x8*)&Pt[wave][qg * 16 + l16][quad * 8];
#pragma unroll
    for (int dg = 0; dg < 4; ++dg)
#pragma unroll
      for (int qg = 0; qg < 2; ++qg)
        o[dg][qg] = __builtin_amdgcn_mfma_f32_16x16x32_bf16(vf[dg], pb[qg], o[dg][qg], 0, 0, 0);
#pragma unroll
    for (int qg = 0; qg < 2; ++qg)
      o[4][qg] = __builtin_amdgcn_mfma_f32_16x16x32_bf16(ones, pb[qg], o[4][qg], 0, 0, 0);
  }
  // ---- epilogue: normalize by l (ones-row), store ctx bf16 [4096][1024] ----
#pragma unroll
  for (int qg = 0; qg < 2; ++qg) {
    const float inv = 1.f / o[4][qg][0];
    const size_t base = (size_t)(b * 2048 + q0 + qg * 16 + l16) * 1024 + h * 64;
#pragma unroll
    for (int dg = 0; dg < 4; ++dg) {
      ushort4 us;
      us.x = f2bf(o[dg][qg][0] * inv); us.y = f2bf(o[dg][qg][1] * inv);
      us.z = f2bf(o[dg][qg][2] * inv); us.w = f2bf(o[dg][qg][3] * inv);
      *(ushort4*)&ctx[base + dg * 16 + quad * 4] = us;
    }
  }
}

// ---------------- launch ----------------
extern "C" void kernel_launch(void* const* d_in, const int* in_sizes, int n_in,
                              void* d_out, int out_size, void* d_ws, size_t ws_size,
                              hipStream_t stream) {
  const float* x  = (const float*)d_in[0];
  const float* Wq = (const float*)d_in[1];
  const float* Wk = (const float*)d_in[2];
  const float* Wv = (const float*)d_in[3];
  const float* Wo = (const float*)d_in[4];
  const float* bo = (const float*)d_in[5];
  float* out = (float*)d_out;

  // workspace layout (48 MB total)
  char* ws = (char*)d_ws;
  unsigned short* Xb    = (unsigned short*)(ws);                          //  8 MB [4096][1024]
  unsigned short* Wqkvt = (unsigned short*)(ws + (size_t)8  * 1048576);   //  6 MB [3072][1024]
  unsigned short* Wot   = (unsigned short*)(ws + (size_t)14 * 1048576);   //  2 MB [1024][1024]
  unsigned short* Qhb   = (unsigned short*)(ws + (size_t)16 * 1048576);   //  8 MB [32][2048][64]
  unsigned short* Khb   = (unsigned short*)(ws + (size_t)24 * 1048576);   //  8 MB [32][2048][64]
  unsigned short* Vtb   = (unsigned short*)(ws + (size_t)32 * 1048576);   //  8 MB [32][64][64][32]
  unsigned short* CT    = (unsigned short*)(ws + (size_t)40 * 1048576);   //  8 MB [4096][1024]

  cast_kernel<<<4096, 256, 0, stream>>>(x, Xb, 1048576);
  transpose_cast<<<dim3(32, 32, 4), 256, 0, stream>>>(Wq, Wk, Wv, Wo, Wqkvt, Wot);
  gemm_bt<1><<<dim3(24, 32), 256, 0, stream>>>(Xb, Wqkvt, Qhb, Khb, Vtb, nullptr, 4096, 3072, 1024);
  attn_kernel<<<dim3(16, 32), 256, 0, stream>>>(Qhb, Khb, Vtb, CT);
  gemm_bt<0><<<dim3(8, 32), 256, 0, stream>>>(CT, Wot, out, nullptr, nullptr, bo, 4096, 1024, 1024);
}

// Round 5
// 223.907 us; speedup vs baseline: 1.5492x; 1.0121x over previous
//
#include <hip/hip_runtime.h>
#include <hip/hip_bf16.h>
#include <math.h>

typedef __attribute__((ext_vector_type(8))) short bf16x8;
typedef __attribute__((ext_vector_type(8))) unsigned short u16x8;
typedef __attribute__((ext_vector_type(4))) float f32x4;

__device__ __forceinline__ unsigned short f2bf(float f) {
  union { float f; unsigned u; } c; c.f = f;
  unsigned u = c.u;
  u += 0x7fffu + ((u >> 16) & 1u);   // round-to-nearest-even
  return (unsigned short)(u >> 16);
}
__device__ __forceinline__ unsigned fb(float x) {
  union { float f; unsigned u; } c; c.f = x; return c.u;
}
// async global->LDS, 16B per lane; LDS dest must be wave-uniform base + lane*16
__device__ __forceinline__ void async16(const unsigned short* g, unsigned short* l) {
  __builtin_amdgcn_global_load_lds(
      (const __attribute__((address_space(1))) unsigned int*)g,
      (__attribute__((address_space(3))) unsigned int*)l, 16, 0, 0);
}

// ---------------- cast fp32 -> bf16 (vectorized) ----------------
__global__ __launch_bounds__(256) void cast_kernel(const float* __restrict__ in,
                                                   unsigned short* __restrict__ out,
                                                   int n4) {
  int i = blockIdx.x * 256 + threadIdx.x;
  if (i >= n4) return;
  float4 v = ((const float4*)in)[i];
  ushort4 o;
  o.x = f2bf(v.x); o.y = f2bf(v.y); o.z = f2bf(v.z); o.w = f2bf(v.w);
  ((ushort4*)out)[i] = o;
}

// ------------- transpose+cast 1024x1024 fp32 -> bf16 (N x K) -------------
__global__ __launch_bounds__(256) void transpose_cast(
    const float* __restrict__ Wq, const float* __restrict__ Wk,
    const float* __restrict__ Wv, const float* __restrict__ Wo,
    unsigned short* __restrict__ Wqkvt, unsigned short* __restrict__ Wot) {
  __shared__ float t[32][33];
  int z = blockIdx.z;
  const float* src = (z == 0) ? Wq : (z == 1) ? Wk : (z == 2) ? Wv : Wo;
  unsigned short* dst = (z < 3) ? (Wqkvt + (size_t)z * 1024 * 1024) : Wot;
  int tx = threadIdx.x & 31, ty = threadIdx.x >> 5;
  int bx = blockIdx.x, by = blockIdx.y;
#pragma unroll
  for (int i = 0; i < 4; ++i)
    t[ty + i * 8][tx] = src[(size_t)(by * 32 + ty + i * 8) * 1024 + bx * 32 + tx];
  __syncthreads();
#pragma unroll
  for (int i = 0; i < 4; ++i)
    dst[(size_t)(bx * 32 + ty + i * 8) * 1024 + by * 32 + tx] = f2bf(t[tx][ty + i * 8]);
}

// ---------------- QKV GEMM: 128x128 tile, head-major epilogue ----------------
// col<1024 -> Qh[bh][s][64]; col<2048 -> Kh[bh][s][64];
// col>=2048 -> tiled Vt[bh][s>>5][d][32]  (all bf16)
__global__ __launch_bounds__(256) void gemm_qkv(
    const unsigned short* __restrict__ A, const unsigned short* __restrict__ Bt,
    unsigned short* __restrict__ Qh, unsigned short* __restrict__ Kh,
    unsigned short* __restrict__ Vt, int K) {
  __shared__ unsigned short As[128][32];  // unpadded: global_load_lds lane ordering
  __shared__ unsigned short Bs[128][32];
  const int tid = threadIdx.x;
  const int wave = tid >> 6, lane = tid & 63;
  const int quad = lane >> 4, l16 = lane & 15;
  const int m0 = blockIdx.y * 128, n0 = blockIdx.x * 128;
  const int wm = (wave >> 1) * 64, wn = (wave & 1) * 64;
  const int srow = tid >> 2, sch = (tid & 3) * 8;  // LDS byte addr = tid*16
  f32x4 acc[4][4] = {};

  for (int k0 = 0; k0 < K; k0 += 32) {
    __syncthreads();
    async16(A  + (size_t)(m0 + srow) * K + k0 + sch, &As[srow][sch]);
    async16(Bt + (size_t)(n0 + srow) * K + k0 + sch, &Bs[srow][sch]);
    async16(A  + (size_t)(m0 + srow + 64) * K + k0 + sch, &As[srow + 64][sch]);
    async16(Bt + (size_t)(n0 + srow + 64) * K + k0 + sch, &Bs[srow + 64][sch]);
    __syncthreads();
    bf16x8 af[4], bfr[4];
#pragma unroll
    for (int i = 0; i < 4; ++i) {
      af[i]  = *(const bf16x8*)&As[wm + i * 16 + l16][quad * 8];
      bfr[i] = *(const bf16x8*)&Bs[wn + i * 16 + l16][quad * 8];
    }
#pragma unroll
    for (int mi = 0; mi < 4; ++mi)
#pragma unroll
      for (int ni = 0; ni < 4; ++ni)
        acc[mi][ni] = __builtin_amdgcn_mfma_f32_16x16x32_bf16(af[mi], bfr[ni], acc[mi][ni], 0, 0, 0);
  }

#pragma unroll
  for (int mi = 0; mi < 4; ++mi) {
#pragma unroll
    for (int ni = 0; ni < 4; ++ni) {
      const int col = n0 + wn + ni * 16 + l16;
      const int token0 = m0 + wm + mi * 16 + quad * 4;
      const int bb = token0 >> 11, s0 = token0 & 2047;
      if (col < 2048) {  // Q or K, head-major [bh][s][64]
        const int hh = (col & 1023) >> 6, d = col & 63;
        unsigned short* dst = (col < 1024) ? Qh : Kh;
        dst += ((size_t)(bb * 16 + hh) * 2048 + s0) * 64 + d;
#pragma unroll
        for (int r = 0; r < 4; ++r) dst[(size_t)r * 64] = f2bf(acc[mi][ni][r]);
      } else {           // V, tiled [bh][s>>5][d][32]
        const int vc = col - 2048, hh = vc >> 6, d = vc & 63;
        ushort4 us;
        us.x = f2bf(acc[mi][ni][0]); us.y = f2bf(acc[mi][ni][1]);
        us.z = f2bf(acc[mi][ni][2]); us.w = f2bf(acc[mi][ni][3]);
        *(ushort4*)&Vt[(((size_t)(bb * 16 + hh) * 64 + (s0 >> 5)) * 64 + d) * 32 + (s0 & 31)] = us;
      }
    }
  }
}

// ---------------- output GEMM: 128x64 tile (512 blocks -> 2/CU) ----------------
__global__ __launch_bounds__(256) void gemm_out(
    const unsigned short* __restrict__ A, const unsigned short* __restrict__ Bt,
    float* __restrict__ C, const float* __restrict__ bias, int N, int K) {
  __shared__ unsigned short As[128][32];
  __shared__ unsigned short Bs[64][32];
  const int tid = threadIdx.x;
  const int wave = tid >> 6, lane = tid & 63;
  const int quad = lane >> 4, l16 = lane & 15;
  const int m0 = blockIdx.y * 128, n0 = blockIdx.x * 64;
  const int wm = (wave >> 1) * 64, wn = (wave & 1) * 32;
  const int srow = tid >> 2, sch = (tid & 3) * 8;
  f32x4 acc[4][2] = {};

  for (int k0 = 0; k0 < K; k0 += 32) {
    __syncthreads();
    async16(A  + (size_t)(m0 + srow) * K + k0 + sch, &As[srow][sch]);
    async16(A  + (size_t)(m0 + srow + 64) * K + k0 + sch, &As[srow + 64][sch]);
    async16(Bt + (size_t)(n0 + srow) * K + k0 + sch, &Bs[srow][sch]);  // srow<64
    __syncthreads();
    bf16x8 af[4], bfr[2];
#pragma unroll
    for (int i = 0; i < 4; ++i)
      af[i] = *(const bf16x8*)&As[wm + i * 16 + l16][quad * 8];
#pragma unroll
    for (int i = 0; i < 2; ++i)
      bfr[i] = *(const bf16x8*)&Bs[wn + i * 16 + l16][quad * 8];
#pragma unroll
    for (int mi = 0; mi < 4; ++mi)
#pragma unroll
      for (int ni = 0; ni < 2; ++ni)
        acc[mi][ni] = __builtin_amdgcn_mfma_f32_16x16x32_bf16(af[mi], bfr[ni], acc[mi][ni], 0, 0, 0);
  }
#pragma unroll
  for (int mi = 0; mi < 4; ++mi)
#pragma unroll
    for (int ni = 0; ni < 2; ++ni) {
      const int col = n0 + wn + ni * 16 + l16;
      const float bv = bias[col];
      const int row0 = m0 + wm + mi * 16 + quad * 4;
#pragma unroll
      for (int r = 0; r < 4; ++r)
        C[(size_t)(row0 + r) * N + col] = acc[mi][ni][r] + bv;
    }
}

// ---------------- causal flash attention: split-K, 64-key merged tiles ----------------
// Qh,Kh: [32 bh][2048][64] bf16. Vt: [32 bh][64 kt][64 d][32 s] bf16.
// grid (64, 32), block 128 (2 waves). Strip s = 63-bx owns queries [s*32,(s+1)*32).
// T = (s+2)>>1 merged 64-key tiles; wave0: [0,T/2), wave1: [T/2,T) incl. diagonal.
// Partials (m, l via ones-MFMA, O^T) merged through LDS; wave0 stores.
__global__ __launch_bounds__(128, 3) void attn_kernel(
    const unsigned short* __restrict__ Qh, const unsigned short* __restrict__ Kh,
    const unsigned short* __restrict__ Vt, unsigned short* __restrict__ ctx) {
  const int s = 63 - blockIdx.x;        // long strips dispatch first
  const int bh = blockIdx.y;
  const int b = bh >> 4, h = bh & 15;
  const int wave = threadIdx.x >> 6, lane = threadIdx.x & 63;
  const int quad = lane >> 4, l16 = lane & 15;
  const int q0 = s * 32;
  const int T = (s + 2) >> 1;
  const int lo = wave ? (T >> 1) : 0;
  const int hi = wave ? T : (T >> 1);

  __shared__ unsigned short Pt[2][32][72];  // per-wave P^T roundtrip (64 keys + pad)
  __shared__ float Os[5][2][64][4];         // wave1 partial O^T (+ l row)
  __shared__ float Ms[2][64];               // wave1 partial m

  const unsigned short* Qp = Qh + (size_t)bh * 2048 * 64;
  const unsigned short* Kg = Kh + (size_t)bh * 2048 * 64;
  const unsigned short* Vg = Vt + (size_t)bh * 64 * 2048;  // 32-key tile t at +t*2048

  bf16x8 qf[2][2];  // B-frag: n=query(l16), k=dim(quad*8+j); [qg][kk]
#pragma unroll
  for (int qg = 0; qg < 2; ++qg)
#pragma unroll
    for (int kk = 0; kk < 2; ++kk)
      qf[qg][kk] = *(const bf16x8*)(Qp + (size_t)(q0 + qg * 16 + l16) * 64 + kk * 32 + quad * 8);

  bf16x8 ones;  // A-frag of 1.0: PV row = sum_k P = l
#pragma unroll
  for (int j = 0; j < 8; ++j) ones[j] = (short)0x3F80;

  f32x4 o[5][2] = {};                 // [dg 0..3]=O^T, [4]=l row; x [qg]
  float m_[2] = {-INFINITY, -INFINITY};
  const float C = 0.18033688f;        // (1/sqrt(64)) * log2(e)

  for (int jt = lo; jt < hi; ++jt) {
    const int k0 = jt * 64;
    // ---- S^T = K Q^T over 64 keys ----
    f32x4 st[4][2] = {};  // [keyg][qg]
#pragma unroll
    for (int keyg = 0; keyg < 4; ++keyg) {
#pragma unroll
      for (int kk = 0; kk < 2; ++kk) {
        bf16x8 kf = *(const bf16x8*)(Kg + (size_t)(k0 + keyg * 16 + l16) * 64 + kk * 32 + quad * 8);
#pragma unroll
        for (int qg = 0; qg < 2; ++qg)
          st[keyg][qg] = __builtin_amdgcn_mfma_f32_16x16x32_bf16(kf, qf[qg][kk], st[keyg][qg], 0, 0, 0);
      }
    }
    // ---- V fragments for this tile (issue early; consumed after softmax) ----
    bf16x8 vf[4][2];  // [dg][half]
#pragma unroll
    for (int dg = 0; dg < 4; ++dg)
#pragma unroll
      for (int half = 0; half < 2; ++half)
        vf[dg][half] = *(const bf16x8*)(Vg + (size_t)(2 * jt + half) * 2048 + (dg * 16 + l16) * 32 + quad * 8);
    // ---- causal mask: only the diagonal (last) tile, owned by wave1 ----
    if (jt == T - 1) {
#pragma unroll
      for (int keyg = 0; keyg < 4; ++keyg)
#pragma unroll
        for (int r = 0; r < 4; ++r) {
          const int key = k0 + keyg * 16 + quad * 4 + r;
#pragma unroll
          for (int qg = 0; qg < 2; ++qg)
            if (key > q0 + qg * 16 + l16) st[keyg][qg][r] = -INFINITY;
        }
    }
    // ---- online softmax over 64 keys: in-register max + 2 shfl ----
    float al[2];
#pragma unroll
    for (int qg = 0; qg < 2; ++qg) {
      float mx = fmaxf(fmaxf(st[0][qg][0], st[0][qg][1]), fmaxf(st[0][qg][2], st[0][qg][3]));
#pragma unroll
      for (int keyg = 1; keyg < 4; ++keyg)
        mx = fmaxf(mx, fmaxf(fmaxf(st[keyg][qg][0], st[keyg][qg][1]),
                             fmaxf(st[keyg][qg][2], st[keyg][qg][3])));
      mx = fmaxf(mx, __shfl_xor(mx, 16));
      mx = fmaxf(mx, __shfl_xor(mx, 32));
      const float mn = fmaxf(m_[qg], mx * C);
      al[qg] = exp2f(m_[qg] - mn);   // == 1.0 exactly when no new max
      m_[qg] = mn;
#pragma unroll
      for (int keyg = 0; keyg < 4; ++keyg) {
        float p0 = exp2f(fmaf(st[keyg][qg][0], C, -mn));
        float p1 = exp2f(fmaf(st[keyg][qg][1], C, -mn));
        float p2 = exp2f(fmaf(st[keyg][qg][2], C, -mn));
        float p3 = exp2f(fmaf(st[keyg][qg][3], C, -mn));
        uint2 pk;  // truncate-to-bf16 pack via v_perm (values in [0,1])
        pk.x = __builtin_amdgcn_perm(fb(p1), fb(p0), 0x07060302u);
        pk.y = __builtin_amdgcn_perm(fb(p3), fb(p2), 0x07060302u);
        *(uint2*)&Pt[wave][qg * 16 + l16][keyg * 16 + quad * 4] = pk;
      }
    }
    // ---- exact skip-rescale ----
    if (__any(fminf(al[0], al[1]) < 1.0f)) {
#pragma unroll
      for (int dg = 0; dg < 5; ++dg)
#pragma unroll
        for (int qg = 0; qg < 2; ++qg)
#pragma unroll
          for (int r = 0; r < 4; ++r) o[dg][qg][r] *= al[qg];
    }
    // ---- O^T += V^T P ; l-row += 1^T P (two 32-key halves chained) ----
    bf16x8 pb[2][2];  // [qg][half]
#pragma unroll
    for (int qg = 0; qg < 2; ++qg)
#pragma unroll
      for (int half = 0; half < 2; ++half)
        pb[qg][half] = *(const bf16x8*)&Pt[wave][qg * 16 + l16][half * 32 + quad * 8];
#pragma unroll
    for (int dg = 0; dg < 4; ++dg)
#pragma unroll
      for (int qg = 0; qg < 2; ++qg) {
        o[dg][qg] = __builtin_amdgcn_mfma_f32_16x16x32_bf16(vf[dg][0], pb[qg][0], o[dg][qg], 0, 0, 0);
        o[dg][qg] = __builtin_amdgcn_mfma_f32_16x16x32_bf16(vf[dg][1], pb[qg][1], o[dg][qg], 0, 0, 0);
      }
#pragma unroll
    for (int qg = 0; qg < 2; ++qg) {
      o[4][qg] = __builtin_amdgcn_mfma_f32_16x16x32_bf16(ones, pb[qg][0], o[4][qg], 0, 0, 0);
      o[4][qg] = __builtin_amdgcn_mfma_f32_16x16x32_bf16(ones, pb[qg][1], o[4][qg], 0, 0, 0);
    }
  }
  // ---- merge the two key-halves (flash combine), wave0 stores ----
  if (wave == 1) {
#pragma unroll
    for (int qg = 0; qg < 2; ++qg) {
      Ms[qg][lane] = m_[qg];
#pragma unroll
      for (int dg = 0; dg < 5; ++dg)
        *(f32x4*)&Os[dg][qg][lane][0] = o[dg][qg];
    }
  }
  __syncthreads();
  if (wave == 0) {
#pragma unroll
    for (int qg = 0; qg < 2; ++qg) {
      const float m1 = Ms[qg][lane];
      const float mn = fmaxf(m_[qg], m1);
      const float a0 = exp2f(m_[qg] - mn), a1 = exp2f(m1 - mn);
#pragma unroll
      for (int dg = 0; dg < 5; ++dg) {
        f32x4 o1 = *(const f32x4*)&Os[dg][qg][lane][0];
#pragma unroll
        for (int r = 0; r < 4; ++r) o[dg][qg][r] = o[dg][qg][r] * a0 + o1[r] * a1;
      }
      const float inv = 1.f / o[4][qg][0];
      const size_t base = (size_t)(b * 2048 + q0 + qg * 16 + l16) * 1024 + h * 64;
#pragma unroll
      for (int dg = 0; dg < 4; ++dg) {
        ushort4 us;
        us.x = f2bf(o[dg][qg][0] * inv); us.y = f2bf(o[dg][qg][1] * inv);
        us.z = f2bf(o[dg][qg][2] * inv); us.w = f2bf(o[dg][qg][3] * inv);
        *(ushort4*)&ctx[base + dg * 16 + quad * 4] = us;
      }
    }
  }
}

// ---------------- launch ----------------
extern "C" void kernel_launch(void* const* d_in, const int* in_sizes, int n_in,
                              void* d_out, int out_size, void* d_ws, size_t ws_size,
                              hipStream_t stream) {
  const float* x  = (const float*)d_in[0];
  const float* Wq = (const float*)d_in[1];
  const float* Wk = (const float*)d_in[2];
  const float* Wv = (const float*)d_in[3];
  const float* Wo = (const float*)d_in[4];
  const float* bo = (const float*)d_in[5];
  float* out = (float*)d_out;

  // workspace layout (48 MB total)
  char* ws = (char*)d_ws;
  unsigned short* Xb    = (unsigned short*)(ws);                          //  8 MB [4096][1024]
  unsigned short* Wqkvt = (unsigned short*)(ws + (size_t)8  * 1048576);   //  6 MB [3072][1024]
  unsigned short* Wot   = (unsigned short*)(ws + (size_t)14 * 1048576);   //  2 MB [1024][1024]
  unsigned short* Qhb   = (unsigned short*)(ws + (size_t)16 * 1048576);   //  8 MB [32][2048][64]
  unsigned short* Khb   = (unsigned short*)(ws + (size_t)24 * 1048576);   //  8 MB [32][2048][64]
  unsigned short* Vtb   = (unsigned short*)(ws + (size_t)32 * 1048576);   //  8 MB [32][64][64][32]
  unsigned short* CT    = (unsigned short*)(ws + (size_t)40 * 1048576);   //  8 MB [4096][1024]

  cast_kernel<<<4096, 256, 0, stream>>>(x, Xb, 1048576);
  transpose_cast<<<dim3(32, 32, 4), 256, 0, stream>>>(Wq, Wk, Wv, Wo, Wqkvt, Wot);
  gemm_qkv<<<dim3(24, 32), 256, 0, stream>>>(Xb, Wqkvt, Qhb, Khb, Vtb, 1024);
  attn_kernel<<<dim3(64, 32), 128, 0, stream>>>(Qhb, Khb, Vtb, CT);
  gemm_out<<<dim3(16, 32), 256, 0, stream>>>(CT, Wot, out, bo, 1024, 1024);
}